// Round 2
// 1735.519 us; speedup vs baseline: 1.1044x; 1.1044x over previous
//
#include <hip/hip_runtime.h>
#include <hip/hip_bf16.h>

// ---------------------------------------------------------------------------
// BiLSTM (persistent bf16-MFMA kernel, register-resident weights + cell state,
// BARRIER-FREE data-flow sync) + CRF forward.
// XCD-local communication groups: grid remapped so each (dir,mt) group = 32
// blocks lands on ONE XCD (bid&7 round-robin); placement VERIFIED at runtime
// via HW_REG_XCC_ID publish+poll; when verified, h exchange uses sc0-only
// (local-L2) loads + write-through stores instead of sc1 (Infinity Cache).
// Fallback = old sc1 path (grid-uniform decision). Safety this revision:
//  (a) CHK array lives INSIDE the FE region (no workspace growth; feats
//      overwrites it after lstm completes),
//  (b) fast-path h store waits expcnt(0) inside the asm (VMEM stores read
//      their data VGPR asynchronously; without the wait the compiler may
//      reuse the register -> garbage/sentinel stored -> consumer hang),
//  (c) fast-path poll has a bounded watchdog that mixes in agent-scope loads
//      (correctness-safe; guarantees forward progress even if the sc0 model
//      were wrong -> no container-killing hang).
constexpr int B_ = 64, S_ = 512, E_ = 300, H_ = 512, T_ = 12;
constexpr int G4 = 4 * H_;          // 2048 gate rows
constexpr int KPADX = 320;          // E padded to 320 (zeros 300..319)
constexpr int KTOT = KPADX + H_;    // 832 total K (x | h)
constexpr int KC_TOT = KTOT / 32;   // 26 MFMA k-chunks
constexpr int KC_X = KPADX / 32;    // 10 x-only chunks (h-independent)
constexpr int NT16 = G4 / 16;       // 128 16-wide n tiles
constexpr float NEGV = -10000.0f;
constexpr int ASTR = 840;           // LDS A-row stride in shorts (832 + 8)
constexpr unsigned SENT = 0xFFFFFFFFu;  // sentinel dword (bf16 pair = -NaN,-NaN)

typedef __attribute__((ext_vector_type(8))) short bf16x8_t;
typedef __attribute__((ext_vector_type(4))) float f32x4_t;

// ---- workspace layout (bytes) ---------------------------------------------
constexpr size_t WC_OFF = 0;
constexpr size_t WC_BYTES = (size_t)2 * NT16 * KC_TOT * 64 * 8 * 2;  // 6,815,744
constexpr size_t XC_OFF = WC_OFF + WC_BYTES;
constexpr size_t XC_BYTES = (size_t)S_ * B_ * KPADX * 2;             // 20,971,520
constexpr size_t HH_OFF = XC_OFF + XC_BYTES;
constexpr size_t HH_BYTES = (size_t)2 * (S_ + 1) * B_ * H_ * 2;      // 67,239,936
constexpr size_t FE_OFF = HH_OFF + HH_BYTES;
constexpr size_t FE_BYTES = (size_t)S_ * B_ * T_ * 4;                // 1,572,864
constexpr size_t LSE_OFF = FE_OFF + FE_BYTES;
// CHK: 256 u32 placement-check slots INSIDE the FE region (feats_kernel runs
// after lstm_persist and fully rewrites FE, so this costs no workspace).
constexpr size_t CHK_OFF = FE_OFF;

// ---------------------------------------------------------------------------
// prep: (1) weights -> bf16 MFMA B-fragment order; (2) h0 -> bf16 h_hist slot
// 0; (3) embedding gather xc[s][b][320] bf16; (4) sentinel-fill hh slots 1..S;
// (5) sentinel-fill the 256-entry XCC placement-check array (in FE region).
__global__ void prep_kernel(const float* __restrict__ Wih_f, const float* __restrict__ Whh_f,
                            const float* __restrict__ Wih_b, const float* __restrict__ Whh_b,
                            const float* __restrict__ h0,
                            const int* __restrict__ tokens, const float* __restrict__ Wemb,
                            char* __restrict__ ws) {
  __hip_bfloat16* wc = (__hip_bfloat16*)(ws + WC_OFF);
  __hip_bfloat16* xc = (__hip_bfloat16*)(ws + XC_OFF);
  __hip_bfloat16* hh = (__hip_bfloat16*)(ws + HH_OFF);
  const int WCN = 2 * NT16 * KC_TOT * 64;   // 425,984
  const int H0N = 2 * B_ * H_;              // 65,536
  const int XCN = S_ * B_ * (KPADX / 8);    // 1,310,720
  const int SFD = (S_ * B_ * H_ * 2) / 16;  // 2,097,152 uint4 per dir
  int idx = blockIdx.x * 256 + threadIdx.x;
  if (idx < WCN) {
    int lane = idx & 63;
    int r = idx >> 6;
    int kc = r % KC_TOT; r /= KC_TOT;
    int tt = r % NT16;
    int dir = r / NT16;
    int n16 = lane & 15, quad = lane >> 4;
    int nt = tt >> 2, gate = tt & 3;
    int j = gate * H_ + nt * 16 + n16;   // original gate row
    int k0 = kc * 32 + quad * 8;
    const float* Wih = dir ? Wih_b : Wih_f;
    const float* Whh = dir ? Whh_b : Whh_f;
    __hip_bfloat16* dst = wc + (size_t)idx * 8;
    #pragma unroll
    for (int jj = 0; jj < 8; jj++) {
      int k = k0 + jj;
      float f;
      if (k < E_) f = Wih[(size_t)j * E_ + k];
      else if (k < KPADX) f = 0.f;
      else f = Whh[(size_t)j * H_ + (k - KPADX)];
      dst[jj] = __float2bfloat16(f);
    }
  } else if (idx < WCN + H0N) {
    int i = idx - WCN;                       // dir*B*H + b*H + h
    int dir = i / (B_ * H_), rem = i % (B_ * H_);
    hh[(size_t)dir * (S_ + 1) * B_ * H_ + rem] = __float2bfloat16(h0[i]);
  } else if (idx < WCN + H0N + XCN) {
    int i = idx - WCN - H0N;                 // sb*40 + c8
    int c8 = i % 40, sb = i / 40;            // sb = s*B + b
    int s = sb >> 6, b = sb & 63;
    int k0 = c8 * 8;
    const float* src = Wemb + (size_t)tokens[(size_t)b * S_ + s] * E_;
    __hip_bfloat16 v[8];
    if (k0 + 8 <= E_) {
      float4 f0 = *(const float4*)(src + k0);
      float4 f1 = *(const float4*)(src + k0 + 4);
      v[0] = __float2bfloat16(f0.x); v[1] = __float2bfloat16(f0.y);
      v[2] = __float2bfloat16(f0.z); v[3] = __float2bfloat16(f0.w);
      v[4] = __float2bfloat16(f1.x); v[5] = __float2bfloat16(f1.y);
      v[6] = __float2bfloat16(f1.z); v[7] = __float2bfloat16(f1.w);
    } else {
      #pragma unroll
      for (int jj = 0; jj < 8; jj++) {
        int k = k0 + jj;
        v[jj] = __float2bfloat16(k < E_ ? src[k] : 0.f);
      }
    }
    *(uint4*)(xc + (size_t)sb * KPADX + k0) = *(const uint4*)v;
  } else if (idx < WCN + H0N + XCN + 2 * SFD) {
    int i = idx - WCN - H0N - XCN;
    int dir = i / SFD, j = i % SFD;
    // sentinel-fill hh[dir][1..S][*][*]
    uint4* dst = (uint4*)(hh + (size_t)dir * (S_ + 1) * B_ * H_ + B_ * H_);
    uint4 sv; sv.x = SENT; sv.y = SENT; sv.z = SENT; sv.w = SENT;
    dst[j] = sv;
  } else if (idx < WCN + H0N + XCN + 2 * SFD + 256) {
    // sentinel-fill the XCC placement-check array
    ((unsigned*)(ws + CHK_OFF))[idx - (WCN + H0N + XCN + 2 * SFD)] = SENT;
  }
}

// ---------------------------------------------------------------------------
// Persistent BiLSTM. grid = 256 = group(8 = dir x mt, == bid&7 -> XCD) x
// nt(32 = bid>>3). block = 256. Weights in registers; cell state in a
// register. NO barrier between blocks: consumers poll h(s) dwords
// (sentinel-initialized); producers store h(s+1) and continue immediately.
__launch_bounds__(256, 1)
__global__ void lstm_persist(const float* __restrict__ bias_f,
                             const float* __restrict__ bias_b,
                             const float* __restrict__ c0,
                             char* __restrict__ ws) {
  __shared__ short pool[16 * ASTR];      // 26,880 B A-tile
  __shared__ float gl[4 * 16 * 17];      // 4,352 B gate exchange
  const int bid = blockIdx.x;
  // --- XCD-local remap: group g = bid&7 (round-robin -> one XCD per group) ---
  const int g = bid & 7, nt = bid >> 3, dir = g >> 2, mt = g & 3;
  const int tid = threadIdx.x, lane = tid & 63, wv = tid >> 6;
  const int quad = lane >> 4, l16 = lane & 15;
  const __hip_bfloat16* wc = (const __hip_bfloat16*)(ws + WC_OFF);
  const __hip_bfloat16* xc = (const __hip_bfloat16*)(ws + XC_OFF);
  unsigned* hh_u = (unsigned*)(ws + HH_OFF);
  unsigned long long* hh_q = (unsigned long long*)(ws + HH_OFF);

  // --- load B fragments into registers, once ---
  bf16x8_t bfr[KC_TOT];
  #pragma unroll
  for (int kc = 0; kc < KC_TOT; kc++) {
    size_t boff = (((size_t)dir * NT16 + (nt * 4 + wv)) * KC_TOT + kc) * 64 + lane;
    bfr[kc] = *(const bf16x8_t*)(wc + boff * 8);
  }
  // --- per-thread cell state + biases ---
  const int bo = tid >> 4, hl = tid & 15;       // batch-offset, h-offset
  const int b = mt * 16 + bo, hg = nt * 16 + hl;
  float c = c0[(size_t)(dir * B_ + b) * H_ + hg];
  const float* bias = dir ? bias_b : bias_f;
  const float bi_i = bias[0 * H_ + hg], bi_f = bias[1 * H_ + hg];
  const float bi_g = bias[2 * H_ + hg], bi_o = bias[3 * H_ + hg];

  // --- placement check: publish XCC id, poll all 256, decide uniformly ------
  int fastu;
  {
    unsigned* chk = (unsigned*)(ws + CHK_OFF);
    unsigned* chkl = (unsigned*)pool;          // reuse LDS as scratch
    if (tid == 0) {
      unsigned xcc;
      asm volatile("s_getreg_b32 %0, hwreg(HW_REG_XCC_ID)" : "=s"(xcc));
      __hip_atomic_store(chk + bid, xcc & 0xFu, __ATOMIC_RELAXED,
                         __HIP_MEMORY_SCOPE_AGENT);
    }
    unsigned myv;
    for (;;) {
      myv = __hip_atomic_load(chk + tid, __ATOMIC_RELAXED, __HIP_MEMORY_SCOPE_AGENT);
      if (myv != SENT) break;
      __builtin_amdgcn_s_sleep(4);
    }
    chkl[tid] = myv;
    __syncthreads();
    bool f = true;
    unsigned mask = 0;
    for (int gg = 0; gg < 8; gg++) {
      unsigned v0 = chkl[gg];
      f = f && (v0 < 32u);
      mask |= (1u << (v0 & 31u));
      for (int m = 1; m < 32; m++) f = f && (chkl[gg + 8 * m] == v0);
    }
    f = f && (__popc(mask) == 8);   // 8 groups on 8 DISTINCT XCDs (garbage guard)
    fastu = __builtin_amdgcn_readfirstlane(f ? 1 : 0);
    __syncthreads();                // before pool reuse below
  }

  // --- pre-stage x(0) into pool x-region (cached loads; xc never stale) ---
  {
    int spos0 = dir ? (S_ - 1) : 0;
    for (int i = tid; i < 16 * 40; i += 256) {
      int row = i / 40, c8 = i % 40;
      *(uint4*)(pool + row * ASTR + c8 * 8) =
          *(const uint4*)(xc + ((size_t)spos0 * B_ + mt * 16 + row) * KPADX + c8 * 8);
    }
  }
  __syncthreads();   // x(0) visible before first x-MFMA phase

  // poll-address map: k=0..7, row = rowb + 2k (batch-offset), c2 (8B column)
  // -> coalesced 512B per wave, LDS b64 conflict-free.
  const int rowb = tid >> 7, c2 = tid & 127;

  for (int s = 0; s < S_; s++) {
    // --- x-part MFMAs FIRST (h-independent; hides under producers' tail) ---
    f32x4_t acc = (f32x4_t)(0.f);
    #pragma unroll
    for (int kc = 0; kc < KC_X; kc++) {
      bf16x8_t af = *(const bf16x8_t*)(pool + l16 * ASTR + kc * 32 + quad * 8);
      acc = __builtin_amdgcn_mfma_f32_16x16x32_bf16(af, bfr[kc], acc, 0, 0, 0);
    }
    // --- poll + load h(s) ---
    const unsigned long long* pb =
        hh_q + ((size_t)(dir * (S_ + 1) + s) * B_ + mt * 16) * (H_ / 4)
             + (size_t)rowb * (H_ / 4) + c2;
    unsigned long long hv[8];
    if (fastu) {
      // sc0 loads: L1-bypass, served by this XCD's L2 (producers co-located,
      // stores write through L1 into the same L2).
      const unsigned long long* q0 = pb;
      const unsigned long long* q1 = pb + 256;
      const unsigned long long* q2 = pb + 512;
      const unsigned long long* q3 = pb + 768;
      const unsigned long long* q4 = pb + 1024;
      const unsigned long long* q5 = pb + 1280;
      const unsigned long long* q6 = pb + 1536;
      const unsigned long long* q7 = pb + 1792;
      int tries = 0;
      for (;;) {
        unsigned long long t0, t1, t2, t3, t4, t5, t6, t7;
        asm volatile(
            "global_load_dwordx2 %0, %8, off sc0\n\t"
            "global_load_dwordx2 %1, %9, off sc0\n\t"
            "global_load_dwordx2 %2, %10, off sc0\n\t"
            "global_load_dwordx2 %3, %11, off sc0\n\t"
            "global_load_dwordx2 %4, %12, off sc0\n\t"
            "global_load_dwordx2 %5, %13, off sc0\n\t"
            "global_load_dwordx2 %6, %14, off sc0\n\t"
            "global_load_dwordx2 %7, %15, off sc0\n\t"
            "s_waitcnt vmcnt(0)"
            : "=&v"(t0), "=&v"(t1), "=&v"(t2), "=&v"(t3),
              "=&v"(t4), "=&v"(t5), "=&v"(t6), "=&v"(t7)
            : "v"(q0), "v"(q1), "v"(q2), "v"(q3),
              "v"(q4), "v"(q5), "v"(q6), "v"(q7)
            : "memory");
        bool ok = ((unsigned)t0 != SENT) && ((unsigned)(t0 >> 32) != SENT) &&
                  ((unsigned)t1 != SENT) && ((unsigned)(t1 >> 32) != SENT) &&
                  ((unsigned)t2 != SENT) && ((unsigned)(t2 >> 32) != SENT) &&
                  ((unsigned)t3 != SENT) && ((unsigned)(t3 >> 32) != SENT) &&
                  ((unsigned)t4 != SENT) && ((unsigned)(t4 >> 32) != SENT) &&
                  ((unsigned)t5 != SENT) && ((unsigned)(t5 >> 32) != SENT) &&
                  ((unsigned)t6 != SENT) && ((unsigned)(t6 >> 32) != SENT) &&
                  ((unsigned)t7 != SENT) && ((unsigned)(t7 >> 32) != SENT);
        if (ok) {
          hv[0] = t0; hv[1] = t1; hv[2] = t2; hv[3] = t3;
          hv[4] = t4; hv[5] = t5; hv[6] = t6; hv[7] = t7;
          break;
        }
        // Watchdog insurance: after ~1024 failed tries also attempt an
        // agent-scope (IC) read. Correctness-safe (each dword written once
        // per replay; non-sentinel => final value). Guarantees progress via
        // L2 eviction/writeback even if the sc0 model were wrong.
        if (++tries > 1024) {
          bool ok2 = true;
          #pragma unroll
          for (int k = 0; k < 8; k++) {
            hv[k] = __hip_atomic_load(pb + k * 256, __ATOMIC_RELAXED,
                                      __HIP_MEMORY_SCOPE_AGENT);
            ok2 = ok2 && ((unsigned)hv[k] != SENT) && ((unsigned)(hv[k] >> 32) != SENT);
          }
          if (ok2) break;
        }
        __builtin_amdgcn_s_sleep(1);
      }
    } else {
      // fallback: device-coherent sc1 path (exactly the baseline behavior)
      bool ok = false;
      while (!ok) {
        ok = true;
        #pragma unroll
        for (int k = 0; k < 8; k++) {
          hv[k] = __hip_atomic_load(pb + k * 256, __ATOMIC_RELAXED,
                                    __HIP_MEMORY_SCOPE_AGENT);
          ok = ok && ((unsigned)hv[k] != SENT) && ((unsigned)(hv[k] >> 32) != SENT);
        }
        if (!ok) __builtin_amdgcn_s_sleep(1);
      }
    }
    #pragma unroll
    for (int k = 0; k < 8; k++)
      *(unsigned long long*)(pool + (rowb + 2 * k) * ASTR + KPADX + c2 * 4) = hv[k];
    __syncthreads();
    // --- h-part MFMAs (same accumulation order as baseline: kc 10..25) ---
    #pragma unroll
    for (int kc = KC_X; kc < KC_TOT; kc++) {
      bf16x8_t af = *(const bf16x8_t*)(pool + l16 * ASTR + kc * 32 + quad * 8);
      acc = __builtin_amdgcn_mfma_f32_16x16x32_bf16(af, bfr[kc], acc, 0, 0, 0);
    }
    __syncthreads();   // pool A-reads done
    // --- gate exchange: C/D row = quad*4+r = batch-offset, col = l16 = hl ---
    #pragma unroll
    for (int r = 0; r < 4; r++)
      gl[(wv * 16 + quad * 4 + r) * 17 + l16] = acc[r];
    // --- overlap: prefetch x(s+1) into pool x-region (h-independent) ---
    if (s + 1 < S_) {
      int sposn = dir ? (S_ - 2 - s) : (s + 1);
      for (int i = tid; i < 16 * 40; i += 256) {
        int row = i / 40, c8 = i % 40;
        *(uint4*)(pool + row * ASTR + c8 * 8) =
            *(const uint4*)(xc + ((size_t)sposn * B_ + mt * 16 + row) * KPADX + c8 * 8);
      }
    }
    __syncthreads();
    // --- elementwise cell update (c in register) ---
    float gi = gl[(0 * 16 + bo) * 17 + hl] + bi_i;
    float gf = gl[(1 * 16 + bo) * 17 + hl] + bi_f;
    float gg = gl[(2 * 16 + bo) * 17 + hl] + bi_g;
    float go = gl[(3 * 16 + bo) * 17 + hl] + bi_o;
    float ii = 1.f / (1.f + __expf(-gi));
    float ff = 1.f / (1.f + __expf(-gf));
    float gt = 1.f - 2.f / (1.f + __expf(2.f * gg));   // tanh
    float oo = 1.f / (1.f + __expf(-go));
    c = ff * c + ii * gt;
    float hv2 = oo * (1.f - 2.f / (1.f + __expf(2.f * c)));
    // --- h store: pack 2 bf16 -> one dword store; fire-and-forget ---
    float hn = __shfl_xor(hv2, 1, 64);    // partner shares (bo, hl^1)
    if ((hl & 1) == 0) {
      unsigned short ulo = __builtin_bit_cast(unsigned short, __float2bfloat16(hv2));
      unsigned short uhi = __builtin_bit_cast(unsigned short, __float2bfloat16(hn));
      unsigned pk = ((unsigned)uhi << 16) | (unsigned)ulo;
      size_t uidx = (((size_t)(dir * (S_ + 1) + s + 1) * B_ + b) * H_ + hg) >> 1;
      if (fastu) {
        // sc0 store: write-through to this XCD's L2 (consumers co-located).
        // expcnt(0) INSIDE the asm: VMEM stores read their data VGPR
        // asynchronously -> must not let the compiler reuse pk's register
        // before the store has consumed it (round-0 hang mechanism).
        asm volatile("global_store_dword %0, %1, off sc0\n\t"
                     "s_waitcnt expcnt(0)"
                     :: "v"(hh_u + uidx), "v"(pk) : "memory");
      } else {
        __hip_atomic_store(hh_u + uidx, pk, __ATOMIC_RELAXED,
                           __HIP_MEMORY_SCOPE_AGENT);
      }
    }
    // no barrier — next iteration's data-poll is the synchronization
  }
}

// ---------------------------------------------------------------------------
// feats[(b*S+s)*T + t] = [hf(s) | hb(s)] . W_out[t,:] + b_out[t]. block per s.
// Output layout [b][s][t] so the CRF scan reads contiguously per batch.
// LDS tile stride padded 1024->1032: the 4 t0-lanes {0,3,6,9} previously all
// hit the same bank (4-way conflict); 1032 spreads them to banks {0,24,16,8}.
__launch_bounds__(256)
__global__ void feats_kernel(const float* __restrict__ Wout,
                             const float* __restrict__ bout,
                             char* __restrict__ ws) {
  __shared__ float wl[12 * 1032];   // 49,536 B
  const int s = blockIdx.x, tid = threadIdx.x;
  for (int i = tid; i < 12 * 1024 / 4; i += 256) {
    int idx4 = i * 4;
    int t = idx4 >> 10, k = idx4 & 1023;
    *(float4*)(wl + t * 1032 + k) = *(const float4*)(Wout + idx4);
  }
  __syncthreads();
  const __hip_bfloat16* hh = (const __hip_bfloat16*)(ws + HH_OFF);
  float* fe = (float*)(ws + FE_OFF);
  int b = tid >> 2, tg = tid & 3, t0 = tg * 3;
  const __hip_bfloat16* hf = hh + (size_t)(0 * (S_ + 1) + s + 1) * B_ * H_ + (size_t)b * H_;
  const __hip_bfloat16* hb = hh + (size_t)(1 * (S_ + 1) + (S_ - s)) * B_ * H_ + (size_t)b * H_;
  float a0 = 0.f, a1 = 0.f, a2 = 0.f;
  for (int half = 0; half < 2; half++) {
    const __hip_bfloat16* hp = half ? hb : hf;
    int wof = half * 512;
    for (int k = 0; k < 512; k += 8) {
      uint4 raw = *(const uint4*)(hp + k);
      const __hip_bfloat16* hv = (const __hip_bfloat16*)&raw;
      float hfl[8];
      #pragma unroll
      for (int j = 0; j < 8; j++) hfl[j] = __bfloat162float(hv[j]);
      #pragma unroll
      for (int j = 0; j < 8; j++) {
        a0 += hfl[j] * wl[(t0 + 0) * 1032 + wof + k + j];
        a1 += hfl[j] * wl[(t0 + 1) * 1032 + wof + k + j];
        a2 += hfl[j] * wl[(t0 + 2) * 1032 + wof + k + j];
      }
    }
  }
  float* o = fe + ((size_t)b * S_ + s) * T_;
  o[t0 + 0] = a0 + bout[t0 + 0];
  o[t0 + 1] = a1 + bout[t0 + 1];
  o[t0 + 2] = a2 + bout[t0 + 2];
}

// ---------------------------------------------------------------------------
// CRF forward scan: one wave per batch element; lane = next-tag (<12).
// Software-pipelined: load feat(s+1) while computing step s.
__launch_bounds__(64)
__global__ void crf_kernel(const int* __restrict__ lengths,
                           const float* __restrict__ trans,
                           char* __restrict__ ws) {
  const int b = blockIdx.x, lane = threadIdx.x;
  const float* fe = (const float*)(ws + FE_OFF);
  float* lse = (float*)(ws + LSE_OFF);
  const float* fb = fe + (size_t)b * S_ * T_;
  float tr[12];
  #pragma unroll
  for (int p = 0; p < 12; p++) tr[p] = (lane < 12) ? trans[lane * 12 + p] : 0.f;
  float tstop = (lane < 12) ? trans[11 * 12 + lane] : 0.f;  // STOP row
  float alpha = (lane == 10) ? 0.f : NEGV;                  // START tag
  const int len = lengths[b];
  float feat = (lane < 12) ? fb[lane] : 0.f;
  for (int s = 0; s < S_; s++) {
    float fn = (lane < 12 && s + 1 < S_) ? fb[(size_t)(s + 1) * T_ + lane] : 0.f;
    float av[12];
    #pragma unroll
    for (int p = 0; p < 12; p++) av[p] = __shfl(alpha, p, 64) + tr[p];
    float mx = av[0];
    #pragma unroll
    for (int p = 1; p < 12; p++) mx = fmaxf(mx, av[p]);
    float sum = 0.f;
    #pragma unroll
    for (int p = 0; p < 12; p++) sum += __expf(av[p] - mx);
    float nw = mx + __logf(sum) + feat;
    if (s < len && lane < 12) alpha = nw;
    feat = fn;
  }
  float tv = (lane < 12) ? (alpha + tstop) : -3.0e38f;
  float mx = tv;
  #pragma unroll
  for (int off = 32; off > 0; off >>= 1) mx = fmaxf(mx, __shfl_xor(mx, off, 64));
  float sum = __expf(tv - mx);
  #pragma unroll
  for (int off = 32; off > 0; off >>= 1) sum += __shfl_xor(sum, off, 64);
  if (lane == 0) lse[b] = mx + __logf(sum);
}

__global__ void final_kernel(char* __restrict__ ws, float* __restrict__ out) {
  const float* lse = (const float*)(ws + LSE_OFF);
  float v = lse[threadIdx.x];
  #pragma unroll
  for (int off = 32; off > 0; off >>= 1) v += __shfl_xor(v, off, 64);
  if (threadIdx.x == 0) out[0] = v * (1.f / 64.f);
}

// ---------------------------------------------------------------------------
extern "C" void kernel_launch(void* const* d_in, const int* in_sizes, int n_in,
                              void* d_out, int out_size, void* d_ws, size_t ws_size,
                              hipStream_t stream) {
  (void)in_sizes; (void)n_in; (void)out_size; (void)ws_size;
  const int* tokens = (const int*)d_in[0];
  const int* lengths = (const int*)d_in[1];
  const float* Wemb = (const float*)d_in[2];
  const float* Wih_f = (const float*)d_in[3];
  const float* Whh_f = (const float*)d_in[4];
  const float* b_f = (const float*)d_in[5];
  const float* Wih_b = (const float*)d_in[6];
  const float* Whh_b = (const float*)d_in[7];
  const float* b_b = (const float*)d_in[8];
  const float* h0 = (const float*)d_in[9];
  const float* c0 = (const float*)d_in[10];
  const float* Wout = (const float*)d_in[11];
  const float* bout = (const float*)d_in[12];
  const float* trans = (const float*)d_in[13];
  char* ws = (char*)d_ws;
  float* out = (float*)d_out;

  int prep_items = 2 * NT16 * KC_TOT * 64 + 2 * B_ * H_ + S_ * B_ * (KPADX / 8)
                 + 2 * (S_ * B_ * H_ * 2) / 16 + 256;
  hipLaunchKernelGGL(prep_kernel, dim3((prep_items + 255) / 256), dim3(256), 0, stream,
                     Wih_f, Whh_f, Wih_b, Whh_b, h0, tokens, Wemb, ws);
  hipLaunchKernelGGL(lstm_persist, dim3(256), dim3(256), 0, stream, b_f, b_b, c0, ws);
  hipLaunchKernelGGL(feats_kernel, dim3(S_), dim3(256), 0, stream, Wout, bout, ws);
  hipLaunchKernelGGL(crf_kernel, dim3(B_), dim3(64), 0, stream, lengths, trans, ws);
  hipLaunchKernelGGL(final_kernel, dim3(1), dim3(64), 0, stream, ws, out);
}